// Round 1
// baseline (466.492 us; speedup 1.0000x reference)
//
#include <hip/hip_runtime.h>
#include <hip/hip_bf16.h>

// CausalSelfAttention: x[4,2048,1024] -> qkv proj -> 16-head causal attn -> out proj
// Pipeline: cvt(fp32->bf16) x3 -> gemm_bt<QKV> -> attn -> gemm_bt<OUT>

#define B_ 4
#define T_ 2048
#define C_ 1024
#define H_ 16
#define D_ 64
#define M_ (B_*T_)   // 8192 tokens

typedef __attribute__((ext_vector_type(8))) short short8;
typedef __attribute__((ext_vector_type(4))) float f32x4;

static __device__ __forceinline__ ushort f2bf(float f) {
  __hip_bfloat16 b = __float2bfloat16(f);
  ushort u; __builtin_memcpy(&u, &b, 2); return u;
}

static __device__ __forceinline__ void ld16(const void* g, void* l) {
  __builtin_amdgcn_global_load_lds((const __attribute__((address_space(1))) void*)g,
                                   (__attribute__((address_space(3))) void*)l, 16, 0, 0);
}

static __device__ __forceinline__ f32x4 mfma16(short8 a, short8 b, f32x4 c) {
  return __builtin_amdgcn_mfma_f32_16x16x32_bf16(a, b, c, 0, 0, 0);
}

// ---------------- fp32 -> bf16 convert ----------------
__global__ void cvt_bf16(const float* __restrict__ in, ushort* __restrict__ out, int n4) {
  int i = blockIdx.x * blockDim.x + threadIdx.x;
  int st = gridDim.x * blockDim.x;
  for (; i < n4; i += st) {
    float4 v = ((const float4*)in)[i];
    ushort4 o;
    o.x = f2bf(v.x); o.y = f2bf(v.y); o.z = f2bf(v.z); o.w = f2bf(v.w);
    ((ushort4*)out)[i] = o;
  }
}

// ---------------- C = A @ B^T + bias (both A,B K-major bf16) ----------------
// MODE 0: QKV projection -> scatter to q[B,H,T,D], k[B,H,T,D], vt[B,H,D,T] (bf16)
// MODE 1: out projection -> fp32 d_out
template<int MODE>
__global__ __launch_bounds__(256) void gemm_bt(
    const ushort* __restrict__ A, const ushort* __restrict__ Bm,
    const float* __restrict__ bias, int K,
    ushort* __restrict__ q, ushort* __restrict__ kk, ushort* __restrict__ vt,
    float* __restrict__ outF)
{
  __shared__ ushort Al[128*32];
  __shared__ ushort Bl[128*32];
  const int tid = threadIdx.x;
  const int lane = tid & 63;
  const int w = tid >> 6;
  const int wr = w >> 1, wc = w & 1;
  const int l15 = lane & 15, lhi = lane >> 4;
  const long i0 = (long)blockIdx.y * 128;
  const long j0 = (long)blockIdx.x * 128;

  f32x4 acc[4][4] = {};

  for (int k0 = 0; k0 < K; k0 += 32) {
    __syncthreads();
    {
      int c = tid;
      ld16((const char*)A  + ((i0 + (c >> 2)) * K + k0 + (c & 3) * 8) * 2, (char*)Al + c * 16);
      ld16((const char*)Bm + ((j0 + (c >> 2)) * K + k0 + (c & 3) * 8) * 2, (char*)Bl + c * 16);
      c = tid + 256;
      ld16((const char*)A  + ((i0 + (c >> 2)) * K + k0 + (c & 3) * 8) * 2, (char*)Al + c * 16);
      ld16((const char*)Bm + ((j0 + (c >> 2)) * K + k0 + (c & 3) * 8) * 2, (char*)Bl + c * 16);
    }
    __syncthreads();
    short8 af[4], bf[4];
#pragma unroll
    for (int m = 0; m < 4; m++) af[m] = *(const short8*)&Al[(wr*64 + m*16 + l15)*32 + lhi*8];
#pragma unroll
    for (int n = 0; n < 4; n++) bf[n] = *(const short8*)&Bl[(wc*64 + n*16 + l15)*32 + lhi*8];
#pragma unroll
    for (int m = 0; m < 4; m++)
#pragma unroll
      for (int n = 0; n < 4; n++)
        acc[m][n] = mfma16(af[m], bf[n], acc[m][n]);
  }

#pragma unroll
  for (int m = 0; m < 4; m++) {
#pragma unroll
    for (int n = 0; n < 4; n++) {
#pragma unroll
      for (int r = 0; r < 4; r++) {
        long i = i0 + wr*64 + m*16 + lhi*4 + r;       // token row
        int  j = (int)j0 + wc*64 + n*16 + l15;        // output feature
        float v = acc[m][n][r] + bias[j];
        if (MODE == 0) {
          int b = (int)(i >> 11), t = (int)(i & 2047);
          int sel = j >> 10, cc = j & 1023;
          int h = cc >> 6, d = cc & 63;
          long bh = (long)b * H_ + h;
          ushort bv = f2bf(v);
          if (sel == 0)      q [(bh*T_ + t)*D_ + d] = bv;
          else if (sel == 1) kk[(bh*T_ + t)*D_ + d] = bv;
          else               vt[(bh*D_ + d)*T_ + t] = bv;   // V stored transposed
        } else {
          outF[i * C_ + j] = v;
        }
      }
    }
  }
}

// ---------------- causal flash attention ----------------
// grid (T/64, B*H), 256 threads. Wave w owns q rows q0b+16w..+15.
__global__ __launch_bounds__(256) void attn_k(
    const ushort* __restrict__ Q, const ushort* __restrict__ K,
    const ushort* __restrict__ V, ushort* __restrict__ AO)
{
  __shared__ ushort Kl[32*64];      // [kv][d]
  __shared__ ushort Vl[64*32];      // [d][kv]  (V already transposed in global)
  __shared__ ushort Pl[4][16*32];   // wave-private P buffers
  const int tid = threadIdx.x;
  const int lane = tid & 63;
  const int w = tid >> 6;
  const int l15 = lane & 15, lhi = lane >> 4;
  const int bh = blockIdx.y;
  const int q0b = blockIdx.x * 64;
  const int q0w = q0b + w * 16;

  const ushort* Qb = Q + (size_t)bh * T_ * D_;
  const ushort* Kb = K + (size_t)bh * T_ * D_;
  const ushort* Vb = V + (size_t)bh * D_ * T_;

  short8 qf[2];
#pragma unroll
  for (int s = 0; s < 2; s++)
    qf[s] = *(const short8*)&Qb[(q0w + l15) * D_ + s * 32 + lhi * 8];

  f32x4 o[4] = {};
  float mr[4], lr[4];
#pragma unroll
  for (int r = 0; r < 4; r++) { mr[r] = -1e30f; lr[r] = 0.f; }

  const int nst = (q0b >> 5) + 2;
  for (int st = 0; st < nst; st++) {
    const int kv0 = st * 32;
    __syncthreads();
    // stage K tile [32][64] and Vt tile [64][32]
    ld16((const char*)Kb + ((size_t)(kv0 + (tid >> 3)) * D_ + (tid & 7) * 8) * 2,
         (char*)Kl + tid * 16);
    ld16((const char*)Vb + ((size_t)(tid >> 2) * T_ + kv0 + (tid & 3) * 8) * 2,
         (char*)Vl + tid * 16);
    __syncthreads();
    if (kv0 <= q0w + 15) {
      // S = Q K^T  (16 q rows x 32 kv cols)
      f32x4 sc[2] = {};
#pragma unroll
      for (int c = 0; c < 2; c++) {
        short8 kf0 = *(const short8*)&Kl[(c*16 + l15)*64 + lhi*8];
        short8 kf1 = *(const short8*)&Kl[(c*16 + l15)*64 + 32 + lhi*8];
        sc[c] = mfma16(qf[0], kf0, sc[c]);
        sc[c] = mfma16(qf[1], kf1, sc[c]);
      }
      float sv[2][4];
      const bool needmask = (kv0 + 31 > q0w);
#pragma unroll
      for (int c = 0; c < 2; c++)
#pragma unroll
        for (int r = 0; r < 4; r++) {
          float xv = sc[c][r] * 0.125f;
          if (needmask) {
            int kv = kv0 + c*16 + l15;
            int qi = q0w + lhi*4 + r;
            if (kv > qi) xv = -1e30f;
          }
          sv[c][r] = xv;
        }
      float al[4];
#pragma unroll
      for (int r = 0; r < 4; r++) {
        float t = fmaxf(sv[0][r], sv[1][r]);
#pragma unroll
        for (int mk = 1; mk < 16; mk <<= 1) t = fmaxf(t, __shfl_xor(t, mk, 16));
        float nm = fmaxf(mr[r], t);
        al[r] = __expf(mr[r] - nm);
        mr[r] = nm;
        float p0 = __expf(sv[0][r] - nm);
        float p1 = __expf(sv[1][r] - nm);
        sv[0][r] = p0; sv[1][r] = p1;
        float s2 = p0 + p1;
#pragma unroll
        for (int mk = 1; mk < 16; mk <<= 1) s2 += __shfl_xor(s2, mk, 16);
        lr[r] = lr[r]*al[r] + s2;
      }
#pragma unroll
      for (int n = 0; n < 4; n++)
#pragma unroll
        for (int r = 0; r < 4; r++) o[n][r] *= al[r];
      // P (D-layout) -> LDS -> A-fragment layout (wave-private, no block barrier)
      ushort* P = &Pl[w][0];
#pragma unroll
      for (int c = 0; c < 2; c++)
#pragma unroll
        for (int r = 0; r < 4; r++)
          P[(lhi*4 + r)*32 + c*16 + l15] = f2bf(sv[c][r]);
      asm volatile("s_waitcnt lgkmcnt(0)" ::: "memory");
      short8 pf = *(const short8*)&P[l15*32 + lhi*8];
#pragma unroll
      for (int n = 0; n < 4; n++) {
        short8 vf = *(const short8*)&Vl[(n*16 + l15)*32 + lhi*8];
        o[n] = mfma16(pf, vf, o[n]);
      }
    }
  }
  const int b = bh >> 4, h = bh & 15;
  float inv[4];
#pragma unroll
  for (int r = 0; r < 4; r++) inv[r] = 1.0f / lr[r];
#pragma unroll
  for (int n = 0; n < 4; n++)
#pragma unroll
    for (int r = 0; r < 4; r++) {
      int t = q0w + lhi*4 + r;
      int cc = h*64 + n*16 + l15;
      AO[((size_t)(b*T_ + t))*C_ + cc] = f2bf(o[n][r] * inv[r]);
    }
}

extern "C" void kernel_launch(void* const* d_in, const int* in_sizes, int n_in,
                              void* d_out, int out_size, void* d_ws, size_t ws_size,
                              hipStream_t stream) {
  const float* x     = (const float*)d_in[0];
  const float* w_qkv = (const float*)d_in[1];
  const float* b_qkv = (const float*)d_in[2];
  const float* w_out = (const float*)d_in[3];
  const float* b_out = (const float*)d_in[4];
  float* out = (float*)d_out;

  ushort* xb    = (ushort*)d_ws;                    // 8192*1024
  ushort* wqkvb = xb    + (size_t)M_ * C_;          // 3072*1024
  ushort* woutb = wqkvb + (size_t)3 * C_ * C_;      // 1024*1024
  ushort* q     = woutb + (size_t)C_ * C_;          // [B,H,T,D]
  ushort* kk    = q     + (size_t)M_ * C_;          // [B,H,T,D]
  ushort* vt    = kk    + (size_t)M_ * C_;          // [B,H,D,T]
  ushort* ao    = xb;                               // reuse xb (free after QKV GEMM)

  cvt_bf16<<<1024, 256, 0, stream>>>(x,     xb,    (M_ * C_) / 4);
  cvt_bf16<<<512,  256, 0, stream>>>(w_qkv, wqkvb, (3 * C_ * C_) / 4);
  cvt_bf16<<<256,  256, 0, stream>>>(w_out, woutb, (C_ * C_) / 4);

  gemm_bt<0><<<dim3(3 * C_ / 128, M_ / 128), 256, 0, stream>>>(
      xb, wqkvb, b_qkv, C_, q, kk, vt, nullptr);

  attn_k<<<dim3(T_ / 64, B_ * H_), 256, 0, stream>>>(q, kk, vt, ao);

  gemm_bt<1><<<dim3(C_ / 128, M_ / 128), 256, 0, stream>>>(
      ao, woutb, b_out, C_, nullptr, nullptr, nullptr, out);
}

// Round 2
// 392.741 us; speedup vs baseline: 1.1878x; 1.1878x over previous
//
#include <hip/hip_runtime.h>
#include <hip/hip_bf16.h>

// CausalSelfAttention: x[4,2048,1024] -> qkv proj -> 16-head causal attn -> out proj
// Pipeline: cvt(fp32->bf16) x3 -> gemm_bt<QKV> -> attn (waveflash) -> gemm_bt<OUT>

#define B_ 4
#define T_ 2048
#define C_ 1024
#define H_ 16
#define D_ 64
#define M_ (B_*T_)   // 8192 tokens

typedef __attribute__((ext_vector_type(8))) short short8;
typedef __attribute__((ext_vector_type(4))) float f32x4;

static __device__ __forceinline__ ushort f2bf(float f) {
  __hip_bfloat16 b = __float2bfloat16(f);
  ushort u; __builtin_memcpy(&u, &b, 2); return u;
}

static __device__ __forceinline__ void ld16(const void* g, void* l) {
  __builtin_amdgcn_global_load_lds((const __attribute__((address_space(1))) void*)g,
                                   (__attribute__((address_space(3))) void*)l, 16, 0, 0);
}

static __device__ __forceinline__ f32x4 mfma16(short8 a, short8 b, f32x4 c) {
  return __builtin_amdgcn_mfma_f32_16x16x32_bf16(a, b, c, 0, 0, 0);
}

// ---------------- fp32 -> bf16 convert ----------------
__global__ void cvt_bf16(const float* __restrict__ in, ushort* __restrict__ out, int n4) {
  int i = blockIdx.x * blockDim.x + threadIdx.x;
  int st = gridDim.x * blockDim.x;
  for (; i < n4; i += st) {
    float4 v = ((const float4*)in)[i];
    ushort4 o;
    o.x = f2bf(v.x); o.y = f2bf(v.y); o.z = f2bf(v.z); o.w = f2bf(v.w);
    ((ushort4*)out)[i] = o;
  }
}

// ---------------- C = A @ B^T + bias (both A,B K-major bf16) ----------------
// MODE 0: QKV projection -> scatter to q[B,H,T,D], k[B,H,T,D], vt[B,H,D,T] (bf16)
// MODE 1: out projection -> fp32 d_out
template<int MODE>
__global__ __launch_bounds__(256) void gemm_bt(
    const ushort* __restrict__ A, const ushort* __restrict__ Bm,
    const float* __restrict__ bias, int K,
    ushort* __restrict__ q, ushort* __restrict__ kk, ushort* __restrict__ vt,
    float* __restrict__ outF)
{
  __shared__ ushort Al[128*32];
  __shared__ ushort Bl[128*32];
  const int tid = threadIdx.x;
  const int lane = tid & 63;
  const int w = tid >> 6;
  const int wr = w >> 1, wc = w & 1;
  const int l15 = lane & 15, lhi = lane >> 4;
  const long i0 = (long)blockIdx.y * 128;
  const long j0 = (long)blockIdx.x * 128;

  f32x4 acc[4][4] = {};

  for (int k0 = 0; k0 < K; k0 += 32) {
    __syncthreads();
    {
      int c = tid;
      ld16((const char*)A  + ((i0 + (c >> 2)) * K + k0 + (c & 3) * 8) * 2, (char*)Al + c * 16);
      ld16((const char*)Bm + ((j0 + (c >> 2)) * K + k0 + (c & 3) * 8) * 2, (char*)Bl + c * 16);
      c = tid + 256;
      ld16((const char*)A  + ((i0 + (c >> 2)) * K + k0 + (c & 3) * 8) * 2, (char*)Al + c * 16);
      ld16((const char*)Bm + ((j0 + (c >> 2)) * K + k0 + (c & 3) * 8) * 2, (char*)Bl + c * 16);
    }
    __syncthreads();
    short8 af[4], bf[4];
#pragma unroll
    for (int m = 0; m < 4; m++) af[m] = *(const short8*)&Al[(wr*64 + m*16 + l15)*32 + lhi*8];
#pragma unroll
    for (int n = 0; n < 4; n++) bf[n] = *(const short8*)&Bl[(wc*64 + n*16 + l15)*32 + lhi*8];
#pragma unroll
    for (int m = 0; m < 4; m++)
#pragma unroll
      for (int n = 0; n < 4; n++)
        acc[m][n] = mfma16(af[m], bf[n], acc[m][n]);
  }

#pragma unroll
  for (int m = 0; m < 4; m++) {
#pragma unroll
    for (int n = 0; n < 4; n++) {
#pragma unroll
      for (int r = 0; r < 4; r++) {
        long i = i0 + wr*64 + m*16 + lhi*4 + r;       // token row
        int  j = (int)j0 + wc*64 + n*16 + l15;        // output feature
        float v = acc[m][n][r] + bias[j];
        if (MODE == 0) {
          int b = (int)(i >> 11), t = (int)(i & 2047);
          int sel = j >> 10, cc = j & 1023;
          int h = cc >> 6, d = cc & 63;
          long bh = (long)b * H_ + h;
          ushort bv = f2bf(v);
          if (sel == 0)      q [(bh*T_ + t)*D_ + d] = bv;
          else if (sel == 1) kk[(bh*T_ + t)*D_ + d] = bv;
          else               vt[(bh*D_ + d)*T_ + t] = bv;   // V stored transposed
        } else {
          outF[i * C_ + j] = v;
        }
      }
    }
  }
}

// ---------------- causal flash attention, wave-independent ----------------
// 1D grid of B_*H_*T_/64 = 2048 blocks x 256 threads. Wave w of block L owns
// 16 q rows of head (L & 63); block%8 clusters same-head blocks per XCD.
// Swapped layouts: S'[kv][q] = mfma(K,Q); O'[d][q] = mfma(Vt,P).
#define SCALE_LOG2 0.18033688f   // (1/sqrt(64)) * log2(e)
#define PSTRIDE 36               // u32 stride per q-row (16B-aligned, padded)

__global__ __launch_bounds__(256) void attn_k(
    const ushort* __restrict__ Q, const ushort* __restrict__ K,
    const ushort* __restrict__ V, ushort* __restrict__ AO)
{
  __shared__ uint P2[4][16 * PSTRIDE];
  const int tid = threadIdx.x;
  const int lane = tid & 63;
  const int w = tid >> 6;
  const int l15 = lane & 15, lhi = lane >> 4;
  const int L = blockIdx.x;
  const int bh = L & 63;
  const int qg = ((L >> 6) << 2) + w;     // 0..127
  const int q0w = qg * 16;

  const ushort* Qb = Q + (size_t)bh * T_ * D_;
  const ushort* Kb = K + (size_t)bh * T_ * D_;
  const ushort* Vb = V + (size_t)bh * D_ * T_;   // [d][t]
  uint* P = &P2[w][0];

  // Q as B-fragment: lane holds Q[q = q0w+l15][d = s*32 + lhi*8 + j]
  short8 qf[2];
#pragma unroll
  for (int s = 0; s < 2; s++)
    qf[s] = *(const short8*)&Qb[(q0w + l15) * D_ + s * 32 + lhi * 8];

  f32x4 o[4] = {};          // O'[d][q]: d = n*16 + lhi*4 + r, q = l15
  float m = -1e30f, l = 0.f;

  for (int kv0 = 0; kv0 <= q0w + 15; kv0 += 64) {
    // K as A-fragment: lane holds K[kv = kv0+c*16+l15][d = s*32+lhi*8+j]
    short8 kf[4][2], vf[4][2];
#pragma unroll
    for (int c = 0; c < 4; c++)
#pragma unroll
      for (int s = 0; s < 2; s++)
        kf[c][s] = *(const short8*)&Kb[(size_t)(kv0 + c*16 + l15) * D_ + s*32 + lhi*8];
    // Vt as A-fragment: lane holds Vt[d = n*16+l15][kv = kv0+ks*32+lhi*8+j]
#pragma unroll
    for (int n = 0; n < 4; n++)
#pragma unroll
      for (int ks = 0; ks < 2; ks++)
        vf[n][ks] = *(const short8*)&Vb[(size_t)(n*16 + l15) * T_ + kv0 + ks*32 + lhi*8];

    // S'[kv][q]: lane holds kv = kv0 + c*16 + lhi*4 + r for q = q0w + l15
    f32x4 sc[4];
#pragma unroll
    for (int c = 0; c < 4; c++) {
      f32x4 z = {};
      z = mfma16(kf[c][0], qf[0], z);
      sc[c] = mfma16(kf[c][1], qf[1], z);
    }

    const bool needmask = (kv0 + 63 > q0w);
    float sv[4][4];
    float pm = -1e30f;
#pragma unroll
    for (int c = 0; c < 4; c++)
#pragma unroll
      for (int r = 0; r < 4; r++) {
        float xv = sc[c][r] * SCALE_LOG2;
        if (needmask) {
          int kv = kv0 + c*16 + lhi*4 + r;
          if (kv > q0w + l15) xv = -1e30f;
        }
        sv[c][r] = xv;
        pm = fmaxf(pm, xv);
      }
    pm = fmaxf(pm, __shfl_xor(pm, 16));
    pm = fmaxf(pm, __shfl_xor(pm, 32));
    float nm = fmaxf(m, pm);
    float alpha = __builtin_amdgcn_exp2f(m - nm);
    m = nm;
    float ps = 0.f;
#pragma unroll
    for (int c = 0; c < 4; c++)
#pragma unroll
      for (int r = 0; r < 4; r++) {
        float p = __builtin_amdgcn_exp2f(sv[c][r] - nm);
        sv[c][r] = p;
        ps += p;
      }
    ps += __shfl_xor(ps, 16);
    ps += __shfl_xor(ps, 32);
    l = l * alpha + ps;
#pragma unroll
    for (int n = 0; n < 4; n++)
#pragma unroll
      for (int r = 0; r < 4; r++) o[n][r] *= alpha;

    // Pack P -> bf16 pairs, wave-private LDS relayout to PV B-fragment.
    // P2T[q = l15][kvpair]: pair idx = c*8 + lhi*2 + x  (kv = 2*pair)
#pragma unroll
    for (int c = 0; c < 4; c++) {
      uint a, bb;
      asm("v_cvt_pk_bf16_f32 %0, %1, %2" : "=v"(a)  : "v"(sv[c][0]), "v"(sv[c][1]));
      asm("v_cvt_pk_bf16_f32 %0, %1, %2" : "=v"(bb) : "v"(sv[c][2]), "v"(sv[c][3]));
      uint2 pr; pr.x = a; pr.y = bb;
      *(uint2*)&P[l15 * PSTRIDE + c*8 + lhi*2] = pr;
    }
    asm volatile("s_waitcnt lgkmcnt(0)" ::: "memory");
    __builtin_amdgcn_sched_barrier(0);
    // B-fragment read: lane needs P[kv = ks*32 + lhi*8 + j][q = l15]
#pragma unroll
    for (int ks = 0; ks < 2; ks++) {
      uint4 pw = *(const uint4*)&P[l15 * PSTRIDE + ks*16 + lhi*4];
      short8 pf;
      __builtin_memcpy(&pf, &pw, 16);
#pragma unroll
      for (int n = 0; n < 4; n++)
        o[n] = mfma16(vf[n][ks], pf, o[n]);
    }
  }

  const int b = bh >> 4, h = bh & 15;
  const float invl = 1.0f / l;
  const size_t rowb = (size_t)(b * T_ + q0w + l15) * C_ + h * 64;
#pragma unroll
  for (int n = 0; n < 4; n++) {
    ushort4 ov;
    ov.x = f2bf(o[n][0] * invl);
    ov.y = f2bf(o[n][1] * invl);
    ov.z = f2bf(o[n][2] * invl);
    ov.w = f2bf(o[n][3] * invl);
    *(ushort4*)&AO[rowb + n*16 + lhi*4] = ov;
  }
}

extern "C" void kernel_launch(void* const* d_in, const int* in_sizes, int n_in,
                              void* d_out, int out_size, void* d_ws, size_t ws_size,
                              hipStream_t stream) {
  const float* x     = (const float*)d_in[0];
  const float* w_qkv = (const float*)d_in[1];
  const float* b_qkv = (const float*)d_in[2];
  const float* w_out = (const float*)d_in[3];
  const float* b_out = (const float*)d_in[4];
  float* out = (float*)d_out;

  ushort* xb    = (ushort*)d_ws;                    // 8192*1024
  ushort* wqkvb = xb    + (size_t)M_ * C_;          // 3072*1024
  ushort* woutb = wqkvb + (size_t)3 * C_ * C_;      // 1024*1024
  ushort* q     = woutb + (size_t)C_ * C_;          // [B,H,T,D]
  ushort* kk    = q     + (size_t)M_ * C_;          // [B,H,T,D]
  ushort* vt    = kk    + (size_t)M_ * C_;          // [B,H,D,T]
  ushort* ao    = xb;                               // reuse xb (free after QKV GEMM)

  cvt_bf16<<<1024, 256, 0, stream>>>(x,     xb,    (M_ * C_) / 4);
  cvt_bf16<<<512,  256, 0, stream>>>(w_qkv, wqkvb, (3 * C_ * C_) / 4);
  cvt_bf16<<<256,  256, 0, stream>>>(w_out, woutb, (C_ * C_) / 4);

  gemm_bt<0><<<dim3(3 * C_ / 128, M_ / 128), 256, 0, stream>>>(
      xb, wqkvb, b_qkv, C_, q, kk, vt, nullptr);

  attn_k<<<B_ * H_ * T_ / 64, 256, 0, stream>>>(q, kk, vt, ao);

  gemm_bt<1><<<dim3(C_ / 128, M_ / 128), 256, 0, stream>>>(
      ao, woutb, b_out, C_, nullptr, nullptr, nullptr, out);
}

// Round 4
// 312.757 us; speedup vs baseline: 1.4916x; 1.2557x over previous
//
#include <hip/hip_runtime.h>
#include <hip/hip_bf16.h>

// CausalSelfAttention: x[4,2048,1024] -> qkv proj -> 16-head causal attn -> out proj
// Pipeline: cvt(fp32->bf16) x3 -> gemm_bt<QKV> -> attn (waveflash QBLK=32) -> gemm_bt<OUT>

#define B_ 4
#define T_ 2048
#define C_ 1024
#define H_ 16
#define D_ 64
#define M_ (B_*T_)   // 8192 tokens

typedef __attribute__((ext_vector_type(8))) short short8;
typedef __attribute__((ext_vector_type(4))) float f32x4;

static __device__ __forceinline__ ushort f2bf(float f) {
  __hip_bfloat16 b = __float2bfloat16(f);
  ushort u; __builtin_memcpy(&u, &b, 2); return u;
}

static __device__ __forceinline__ void ld16(const void* g, void* l) {
  __builtin_amdgcn_global_load_lds((const __attribute__((address_space(1))) void*)g,
                                   (__attribute__((address_space(3))) void*)l, 16, 0, 0);
}

static __device__ __forceinline__ f32x4 mfma16(short8 a, short8 b, f32x4 c) {
  return __builtin_amdgcn_mfma_f32_16x16x32_bf16(a, b, c, 0, 0, 0);
}

// ---------------- fp32 -> bf16 convert ----------------
__global__ void cvt_bf16(const float* __restrict__ in, ushort* __restrict__ out, int n4) {
  int i = blockIdx.x * blockDim.x + threadIdx.x;
  int st = gridDim.x * blockDim.x;
  for (; i < n4; i += st) {
    float4 v = ((const float4*)in)[i];
    ushort4 o;
    o.x = f2bf(v.x); o.y = f2bf(v.y); o.z = f2bf(v.z); o.w = f2bf(v.w);
    ((ushort4*)out)[i] = o;
  }
}

// ---------------- C = A @ B^T + bias (both A,B K-major bf16) ----------------
// MODE 0: QKV projection -> scatter to q[B,H,T,D], k[B,H,T,D], vt[B,H,D,T] (bf16)
// MODE 1: out projection -> fp32 d_out
template<int MODE>
__global__ __launch_bounds__(256) void gemm_bt(
    const ushort* __restrict__ A, const ushort* __restrict__ Bm,
    const float* __restrict__ bias, int K,
    ushort* __restrict__ q, ushort* __restrict__ kk, ushort* __restrict__ vt,
    float* __restrict__ outF)
{
  __shared__ ushort Al[128*32];
  __shared__ ushort Bl[128*32];
  const int tid = threadIdx.x;
  const int lane = tid & 63;
  const int w = tid >> 6;
  const int wr = w >> 1, wc = w & 1;
  const int l15 = lane & 15, lhi = lane >> 4;
  const long i0 = (long)blockIdx.y * 128;
  const long j0 = (long)blockIdx.x * 128;

  f32x4 acc[4][4] = {};

  for (int k0 = 0; k0 < K; k0 += 32) {
    __syncthreads();
    {
      int c = tid;
      ld16((const char*)A  + ((i0 + (c >> 2)) * K + k0 + (c & 3) * 8) * 2, (char*)Al + c * 16);
      ld16((const char*)Bm + ((j0 + (c >> 2)) * K + k0 + (c & 3) * 8) * 2, (char*)Bl + c * 16);
      c = tid + 256;
      ld16((const char*)A  + ((i0 + (c >> 2)) * K + k0 + (c & 3) * 8) * 2, (char*)Al + c * 16);
      ld16((const char*)Bm + ((j0 + (c >> 2)) * K + k0 + (c & 3) * 8) * 2, (char*)Bl + c * 16);
    }
    __syncthreads();
    short8 af[4], bf[4];
#pragma unroll
    for (int m = 0; m < 4; m++) af[m] = *(const short8*)&Al[(wr*64 + m*16 + l15)*32 + lhi*8];
#pragma unroll
    for (int n = 0; n < 4; n++) bf[n] = *(const short8*)&Bl[(wc*64 + n*16 + l15)*32 + lhi*8];
#pragma unroll
    for (int m = 0; m < 4; m++)
#pragma unroll
      for (int n = 0; n < 4; n++)
        acc[m][n] = mfma16(af[m], bf[n], acc[m][n]);
  }

#pragma unroll
  for (int m = 0; m < 4; m++) {
#pragma unroll
    for (int n = 0; n < 4; n++) {
#pragma unroll
      for (int r = 0; r < 4; r++) {
        long i = i0 + wr*64 + m*16 + lhi*4 + r;       // token row
        int  j = (int)j0 + wc*64 + n*16 + l15;        // output feature
        float v = acc[m][n][r] + bias[j];
        if (MODE == 0) {
          int b = (int)(i >> 11), t = (int)(i & 2047);
          int sel = j >> 10, cc = j & 1023;
          int h = cc >> 6, d = cc & 63;
          long bh = (long)b * H_ + h;
          ushort bv = f2bf(v);
          if (sel == 0)      q [(bh*T_ + t)*D_ + d] = bv;
          else if (sel == 1) kk[(bh*T_ + t)*D_ + d] = bv;
          else               vt[(bh*D_ + d)*T_ + t] = bv;   // V stored transposed
        } else {
          outF[i * C_ + j] = v;
        }
      }
    }
  }
}

// ---------------- causal flash attention, wave-independent, QBLK=32 ----------------
// 1024 blocks x 256 threads. Wave w owns 32 q rows (two 16-row groups sharing K/V).
// XCD-chunked: XCD (b&7) handles heads [8x,8x+8) => 4MB K/V = one L2.
// Long blocks (high q) launch first within each XCD to absorb causal imbalance.
// Swapped layouts: S'[kv][q] = mfma(K,Q); O'[d][q] = mfma(Vt,P).
#define SCALE_LOG2 0.18033688f   // (1/sqrt(64)) * log2(e)
#define PSTRIDE 36               // u32 stride per q-row (16B-aligned, padded)

__global__ __launch_bounds__(256) void attn_k(
    const ushort* __restrict__ Q, const ushort* __restrict__ K,
    const ushort* __restrict__ V, ushort* __restrict__ AO)
{
  __shared__ uint P2[8][16 * PSTRIDE];
  const int tid = threadIdx.x;
  const int lane = tid & 63;
  const int w = tid >> 6;
  const int l15 = lane & 15, lhi = lane >> 4;
  const int bb = blockIdx.x;
  const int x = bb & 7, ii = bb >> 3;     // ii in [0,128)
  const int bh = (x << 3) | (ii >> 4);    // 64 heads, 8 per XCD
  const int chunk = 15 - (ii & 15);       // long blocks first
  const int qg = chunk * 4 + w;           // 0..63
  const int q0w = qg * 32;

  const ushort* Qb = Q + (size_t)bh * T_ * D_;
  const ushort* Kb = K + (size_t)bh * T_ * D_;
  const ushort* Vb = V + (size_t)bh * D_ * T_;   // [d][t]

  // Q as B-fragment: lane holds Q[q = q0w+g*16+l15][d = s*32 + lhi*8 + j]
  short8 qf[2][2];
#pragma unroll
  for (int g = 0; g < 2; g++)
#pragma unroll
    for (int s = 0; s < 2; s++)
      qf[g][s] = *(const short8*)&Qb[(q0w + g*16 + l15) * D_ + s * 32 + lhi * 8];

  f32x4 o[2][4] = {};       // O'[d][q]: d = n*16 + lhi*4 + r, q = l15 (per group)
  float m[2] = {-1e30f, -1e30f}, l[2] = {0.f, 0.f};

  // Prefetched K fragment for the current step.
  short8 kf[4][2];
#pragma unroll
  for (int c = 0; c < 4; c++)
#pragma unroll
    for (int s = 0; s < 2; s++)
      kf[c][s] = *(const short8*)&Kb[(size_t)(c*16 + l15) * D_ + s*32 + lhi*8];

  for (int kv0 = 0; kv0 <= q0w + 31; kv0 += 64) {
    // Vt as A-fragment: lane holds Vt[d = n*16+l15][kv = kv0+ks*32+lhi*8+j]
    short8 vf[4][2];
#pragma unroll
    for (int n = 0; n < 4; n++)
#pragma unroll
      for (int ks = 0; ks < 2; ks++)
        vf[n][ks] = *(const short8*)&Vb[(size_t)(n*16 + l15) * T_ + kv0 + ks*32 + lhi*8];

    // S'[kv][q]: lane holds kv = kv0 + c*16 + lhi*4 + r for q = q0w + g*16 + l15
    f32x4 sc[2][4];
    __builtin_amdgcn_s_setprio(1);
#pragma unroll
    for (int g = 0; g < 2; g++)
#pragma unroll
      for (int c = 0; c < 4; c++) {
        f32x4 z = {};
        z = mfma16(kf[c][0], qf[g][0], z);
        sc[g][c] = mfma16(kf[c][1], qf[g][1], z);
      }
    __builtin_amdgcn_s_setprio(0);

    // Prefetch K fragment for next step (registers freed by the MFMAs above).
    {
      int kvn = kv0 + 64;
      if (kvn > T_ - 64) kvn = T_ - 64;   // clamp: values unused on last step
#pragma unroll
      for (int c = 0; c < 4; c++)
#pragma unroll
        for (int s = 0; s < 2; s++)
          kf[c][s] = *(const short8*)&Kb[(size_t)(kvn + c*16 + l15) * D_ + s*32 + lhi*8];
    }

    // Online softmax per q group (independent -> ILP).
#pragma unroll
    for (int g = 0; g < 2; g++) {
      const bool needmask = (kv0 + 63 > q0w + g*16);
      float sv[4][4];
      float pm = -1e30f;
#pragma unroll
      for (int c = 0; c < 4; c++)
#pragma unroll
        for (int r = 0; r < 4; r++) {
          float xv = sc[g][c][r] * SCALE_LOG2;
          if (needmask) {
            int kv = kv0 + c*16 + lhi*4 + r;
            if (kv > q0w + g*16 + l15) xv = -1e30f;
          }
          sv[c][r] = xv;
          pm = fmaxf(pm, xv);
        }
      pm = fmaxf(pm, __shfl_xor(pm, 16));
      pm = fmaxf(pm, __shfl_xor(pm, 32));
      float nm = fmaxf(m[g], pm);
      float alpha = __builtin_amdgcn_exp2f(m[g] - nm);
      m[g] = nm;
      float ps = 0.f;
#pragma unroll
      for (int c = 0; c < 4; c++)
#pragma unroll
        for (int r = 0; r < 4; r++) {
          float p = __builtin_amdgcn_exp2f(sv[c][r] - nm);
          sv[c][r] = p;
          ps += p;
        }
      ps += __shfl_xor(ps, 16);
      ps += __shfl_xor(ps, 32);
      l[g] = l[g] * alpha + ps;
#pragma unroll
      for (int n = 0; n < 4; n++)
#pragma unroll
        for (int r = 0; r < 4; r++) o[g][n][r] *= alpha;

      // Pack P -> bf16 pairs into wave-private LDS (relayout to PV B-fragment).
      uint* P = &P2[w*2 + g][0];
#pragma unroll
      for (int c = 0; c < 4; c++) {
        uint a, bq;
        asm("v_cvt_pk_bf16_f32 %0, %1, %2" : "=v"(a)  : "v"(sv[c][0]), "v"(sv[c][1]));
        asm("v_cvt_pk_bf16_f32 %0, %1, %2" : "=v"(bq) : "v"(sv[c][2]), "v"(sv[c][3]));
        uint2 pr; pr.x = a; pr.y = bq;
        *(uint2*)&P[l15 * PSTRIDE + c*8 + lhi*2] = pr;
      }
    }
    asm volatile("s_waitcnt lgkmcnt(0)" ::: "memory");
    __builtin_amdgcn_sched_barrier(0);
    // B-fragment read: lane needs P[kv = ks*32 + lhi*8 + j][q = l15]
    short8 pf[2][2];
#pragma unroll
    for (int g = 0; g < 2; g++)
#pragma unroll
      for (int ks = 0; ks < 2; ks++) {
        uint4 pw = *(const uint4*)&P2[w*2 + g][l15 * PSTRIDE + ks*16 + lhi*4];
        __builtin_memcpy(&pf[g][ks], &pw, 16);
      }
    __builtin_amdgcn_s_setprio(1);
#pragma unroll
    for (int g = 0; g < 2; g++)
#pragma unroll
      for (int n = 0; n < 4; n++) {
        o[g][n] = mfma16(vf[n][0], pf[g][0], o[g][n]);
        o[g][n] = mfma16(vf[n][1], pf[g][1], o[g][n]);
      }
    __builtin_amdgcn_s_setprio(0);
  }

  const int b = bh >> 4, h = bh & 15;
#pragma unroll
  for (int g = 0; g < 2; g++) {
    const float invl = 1.0f / l[g];
    const size_t rowb = (size_t)(b * T_ + q0w + g*16 + l15) * C_ + h * 64;
#pragma unroll
    for (int n = 0; n < 4; n++) {
      ushort4 ov;
      ov.x = f2bf(o[g][n][0] * invl);
      ov.y = f2bf(o[g][n][1] * invl);
      ov.z = f2bf(o[g][n][2] * invl);
      ov.w = f2bf(o[g][n][3] * invl);
      *(ushort4*)&AO[rowb + n*16 + lhi*4] = ov;
    }
  }
}

extern "C" void kernel_launch(void* const* d_in, const int* in_sizes, int n_in,
                              void* d_out, int out_size, void* d_ws, size_t ws_size,
                              hipStream_t stream) {
  const float* x     = (const float*)d_in[0];
  const float* w_qkv = (const float*)d_in[1];
  const float* b_qkv = (const float*)d_in[2];
  const float* w_out = (const float*)d_in[3];
  const float* b_out = (const float*)d_in[4];
  float* out = (float*)d_out;

  ushort* xb    = (ushort*)d_ws;                    // 8192*1024
  ushort* wqkvb = xb    + (size_t)M_ * C_;          // 3072*1024
  ushort* woutb = wqkvb + (size_t)3 * C_ * C_;      // 1024*1024
  ushort* q     = woutb + (size_t)C_ * C_;          // [B,H,T,D]
  ushort* kk    = q     + (size_t)M_ * C_;          // [B,H,T,D]
  ushort* vt    = kk    + (size_t)M_ * C_;          // [B,H,D,T]
  ushort* ao    = xb;                               // reuse xb (free after QKV GEMM)

  cvt_bf16<<<1024, 256, 0, stream>>>(x,     xb,    (M_ * C_) / 4);
  cvt_bf16<<<512,  256, 0, stream>>>(w_qkv, wqkvb, (3 * C_ * C_) / 4);
  cvt_bf16<<<256,  256, 0, stream>>>(w_out, woutb, (C_ * C_) / 4);

  gemm_bt<0><<<dim3(3 * C_ / 128, M_ / 128), 256, 0, stream>>>(
      xb, wqkvb, b_qkv, C_, q, kk, vt, nullptr);

  // 4 waves x 32 q-rows = 128 rows per block -> B*H*T/128 = 1024 blocks.
  attn_k<<<B_ * H_ * T_ / 128, 256, 0, stream>>>(q, kk, vt, ao);

  gemm_bt<1><<<dim3(C_ / 128, M_ / 128), 256, 0, stream>>>(
      ao, woutb, b_out, C_, nullptr, nullptr, nullptr, out);
}